// Round 2
// baseline (282.317 us; speedup 1.0000x reference)
//
#include <hip/hip_runtime.h>

#define DOUT 256          // embedding dim
#define NROWS 49152       // 64 king squares * 12 planes * 64 squares
#define SCAN_THREADS 1024

__device__ __forceinline__ float4 ld4(const float* p) {
  return *reinterpret_cast<const float4*>(p);
}

// ---------------- exclusive prefix scan of lengths -> offs ----------------
__global__ __launch_bounds__(SCAN_THREADS) void scan_kernel(
    const int* __restrict__ lengths, int* __restrict__ offs, int n) {
  __shared__ int part[SCAN_THREADS];
  const int t = threadIdx.x;
  const int chunk = (n + SCAN_THREADS - 1) / SCAN_THREADS;
  int s = 0;
  for (int i = 0; i < chunk; ++i) {
    int idx = t * chunk + i;
    if (idx < n) s += lengths[idx];
  }
  part[t] = s;
  __syncthreads();
  // Hillis-Steele inclusive scan
  for (int off = 1; off < SCAN_THREADS; off <<= 1) {
    int v = (t >= off) ? part[t - off] : 0;
    __syncthreads();
    part[t] += v;
    __syncthreads();
  }
  int run = part[t] - s;  // exclusive base of this thread's chunk
  for (int i = 0; i < chunk; ++i) {
    int idx = t * chunk + i;
    if (idx < n) { offs[idx] = run; run += lengths[idx]; }
  }
}

// ---------------- materialize merged = tiles + (pieces+ranks+files)*mask --
__global__ __launch_bounds__(256) void materialize_kernel(
    const float* __restrict__ tiles, const float* __restrict__ pieces,
    const float* __restrict__ ranks, const float* __restrict__ files,
    const float* __restrict__ mask, float* __restrict__ merged) {
  const int row = (blockIdx.x << 2) + (threadIdx.x >> 6);  // 0..NROWS-1
  const int lane = threadIdx.x & 63;
  const int p = row & 63;       // square within plane: r*8+f
  const int sk = row >> 6;      // s*12 + k
  const int r = p >> 3, f = p & 7;
  const float m = mask[row];
  const int d0 = lane << 2;
  float4 t = ld4(tiles + (size_t)row * DOUT + d0);
  float4 pc = ld4(pieces + (size_t)sk * DOUT + d0);
  float4 rk = ld4(ranks + ((size_t)(sk * 8 + r)) * DOUT + d0);
  float4 fl = ld4(files + ((size_t)(sk * 8 + f)) * DOUT + d0);
  float4 o;
  o.x = fmaf(pc.x + rk.x + fl.x, m, t.x);
  o.y = fmaf(pc.y + rk.y + fl.y, m, t.y);
  o.z = fmaf(pc.z + rk.z + fl.z, m, t.z);
  o.w = fmaf(pc.w + rk.w + fl.w, m, t.w);
  *reinterpret_cast<float4*>(merged + (size_t)row * DOUT + d0) = o;
}

// ---------------- gather: one wave per bag ----------------
template <bool MAT>
__global__ __launch_bounds__(256) void gather_kernel(
    const float* __restrict__ merged,
    const float* __restrict__ tiles, const float* __restrict__ pieces,
    const float* __restrict__ ranks, const float* __restrict__ files,
    const float* __restrict__ mask,
    const int* __restrict__ values, const int* __restrict__ lengths,
    const int* __restrict__ kings, const int* __restrict__ offs,
    float* __restrict__ out, int n_bags) {
  const int bag = (blockIdx.x << 2) + (threadIdx.x >> 6);
  const int lane = threadIdx.x & 63;
  if (bag >= n_bags) return;
  const int start = offs[bag];
  const int len = lengths[bag];
  const int km = kings[2 * bag];
  const int kw = kings[2 * bag + 1];
  const int sw = ((7 - (kw >> 3)) << 3) + (kw & 7);  // flipped waiter king sq
  const int d0 = lane << 2;

  float ax = 0.f, ay = 0.f, az = 0.f, aw = 0.f;
  float bx = 0.f, by = 0.f, bz = 0.f, bw = 0.f;

  int v = (len > 0) ? values[start] : 0;
  for (int i = 0; i < len; ++i) {
    const int vn = (i + 1 < len) ? values[start + i + 1] : 0;  // prefetch idx
    const int k = v >> 6, p = v & 63;
    const int r = p >> 3, f = p & 7;
    const int rowA = (km * 12 + k) * 64 + p;
    const int k2 = (k >= 6) ? (k - 6) : (k + 6);
    const int r2 = 7 - r;
    const int rowB = (sw * 12 + k2) * 64 + (r2 << 3) + f;
    float4 a, b;
    if (MAT) {
      a = ld4(merged + (size_t)rowA * DOUT + d0);
      b = ld4(merged + (size_t)rowB * DOUT + d0);
    } else {
      {
        const int sk = km * 12 + k;
        const float m = mask[rowA];
        float4 t = ld4(tiles + (size_t)rowA * DOUT + d0);
        float4 pc = ld4(pieces + (size_t)sk * DOUT + d0);
        float4 rk = ld4(ranks + (size_t)(sk * 8 + r) * DOUT + d0);
        float4 fl = ld4(files + (size_t)(sk * 8 + f) * DOUT + d0);
        a.x = fmaf(pc.x + rk.x + fl.x, m, t.x);
        a.y = fmaf(pc.y + rk.y + fl.y, m, t.y);
        a.z = fmaf(pc.z + rk.z + fl.z, m, t.z);
        a.w = fmaf(pc.w + rk.w + fl.w, m, t.w);
      }
      {
        const int sk2 = sw * 12 + k2;
        const float m = mask[rowB];
        float4 t = ld4(tiles + (size_t)rowB * DOUT + d0);
        float4 pc = ld4(pieces + (size_t)sk2 * DOUT + d0);
        float4 rk = ld4(ranks + (size_t)(sk2 * 8 + r2) * DOUT + d0);
        float4 fl = ld4(files + (size_t)(sk2 * 8 + f) * DOUT + d0);
        b.x = fmaf(pc.x + rk.x + fl.x, m, t.x);
        b.y = fmaf(pc.y + rk.y + fl.y, m, t.y);
        b.z = fmaf(pc.z + rk.z + fl.z, m, t.z);
        b.w = fmaf(pc.w + rk.w + fl.w, m, t.w);
      }
    }
    ax += a.x; ay += a.y; az += a.z; aw += a.w;
    bx += b.x; by += b.y; bz += b.z; bw += b.w;
    v = vn;
  }

  float4 oa, ob;
  oa.x = fminf(fmaxf(ax, 0.f), 1.f);
  oa.y = fminf(fmaxf(ay, 0.f), 1.f);
  oa.z = fminf(fmaxf(az, 0.f), 1.f);
  oa.w = fminf(fmaxf(aw, 0.f), 1.f);
  ob.x = fminf(fmaxf(bx, 0.f), 1.f);
  ob.y = fminf(fmaxf(by, 0.f), 1.f);
  ob.z = fminf(fmaxf(bz, 0.f), 1.f);
  ob.w = fminf(fmaxf(bw, 0.f), 1.f);
  reinterpret_cast<float4*>(out)[(size_t)bag * 64 + lane] = oa;
  reinterpret_cast<float4*>(out)[(size_t)n_bags * 64 + (size_t)bag * 64 + lane] = ob;
}

extern "C" void kernel_launch(void* const* d_in, const int* in_sizes, int n_in,
                              void* d_out, int out_size, void* d_ws, size_t ws_size,
                              hipStream_t stream) {
  const float* pieces = (const float*)d_in[0];
  const float* ranks  = (const float*)d_in[1];
  const float* files  = (const float*)d_in[2];
  const float* tiles  = (const float*)d_in[3];
  const float* mask   = (const float*)d_in[4];
  const int*   values = (const int*)d_in[5];
  const int*   lengths= (const int*)d_in[6];
  const int*   kings  = (const int*)d_in[7];
  float* out = (float*)d_out;

  const int B = in_sizes[6];  // number of bags

  int* offs = (int*)d_ws;
  const size_t merged_off = 65536;  // bytes reserved for offs
  const size_t needed = merged_off + (size_t)NROWS * DOUT * sizeof(float);
  float* merged = (float*)((char*)d_ws + merged_off);
  const bool mat = (ws_size >= needed);

  scan_kernel<<<1, SCAN_THREADS, 0, stream>>>(lengths, offs, B);

  const int gather_blocks = (B + 3) / 4;
  if (mat) {
    materialize_kernel<<<NROWS / 4, 256, 0, stream>>>(tiles, pieces, ranks, files,
                                                      mask, merged);
    gather_kernel<true><<<gather_blocks, 256, 0, stream>>>(
        merged, tiles, pieces, ranks, files, mask, values, lengths, kings, offs,
        out, B);
  } else {
    gather_kernel<false><<<gather_blocks, 256, 0, stream>>>(
        nullptr, tiles, pieces, ranks, files, mask, values, lengths, kings, offs,
        out, B);
  }
}